// Round 1
// 220.415 us; speedup vs baseline: 1.0061x; 1.0061x over previous
//
#include <hip/hip_runtime.h>

// Hadamard on qubit TARGET=5 of N_QUBITS=24, batch=2, real float32 state.
// Per batch: L = 2^5 = 32, R = 2^18 floats (R4 = 2^16 float4).
// flat float4 index = bl * 2*R4 + r4 ; pair stride = R4.
// y0 = (x0 + x1) * inv_sqrt2 ; y1 = (x0 - x1) * inv_sqrt2.
//
// v2 changes vs v1 (62.9 us est, ~4.3 TB/s):
//  - 2 float4-pairs per thread: 4 independent 16B loads in flight per lane
//    (double the memory-level parallelism; dependent-store chain was the
//    latency-hiding limiter at 2 loads/thread).
//  - nontemporal loads/stores: 268 MB stream > 256 MB L3; avoid LLC
//    allocate-on-write evicting the read stream (fill kernels hit 6.75 TB/s
//    write-only; we sat at ~4.3 mixed).

typedef float f4 __attribute__((ext_vector_type(4)));

__global__ __launch_bounds__(256) void hgate_kernel(const f4* __restrict__ x,
                                                    f4* __restrict__ y) {
    constexpr int R4_LOG2 = 16;                // R/4 = 65536 float4
    constexpr int R4 = 1 << R4_LOG2;
    constexpr int HALF = 1 << 21;              // total threads; each does 2 pairs
    const float s = 0.70710678118654752440f;

    const int t = blockIdx.x * blockDim.x + threadIdx.x;   // [0, 2^21)
    const int u = t + HALF;                                // [2^21, 2^22)

    // idx = (bl << (R4_LOG2+1)) + r4 for each of the two work items
    const int a0 = ((t >> R4_LOG2) << (R4_LOG2 + 1)) + (t & (R4 - 1));
    const int b0 = ((u >> R4_LOG2) << (R4_LOG2 + 1)) + (u & (R4 - 1));
    const int a1 = a0 + R4;
    const int b1 = b0 + R4;

    // Issue all four loads before any dependent use.
    f4 xa0 = __builtin_nontemporal_load(x + a0);
    f4 xa1 = __builtin_nontemporal_load(x + a1);
    f4 xb0 = __builtin_nontemporal_load(x + b0);
    f4 xb1 = __builtin_nontemporal_load(x + b1);

    f4 ya0 = (xa0 + xa1) * s;
    f4 ya1 = (xa0 - xa1) * s;
    f4 yb0 = (xb0 + xb1) * s;
    f4 yb1 = (xb0 - xb1) * s;

    __builtin_nontemporal_store(ya0, y + a0);
    __builtin_nontemporal_store(ya1, y + a1);
    __builtin_nontemporal_store(yb0, y + b0);
    __builtin_nontemporal_store(yb1, y + b1);
}

extern "C" void kernel_launch(void* const* d_in, const int* in_sizes, int n_in,
                              void* d_out, int out_size, void* d_ws, size_t ws_size,
                              hipStream_t stream) {
    const f4* x = (const f4*)d_in[0];
    f4* y = (f4*)d_out;
    const int total_threads = 1 << 21;   // 2 float4-pairs per thread
    const int block = 256;
    const int grid = total_threads / block;   // 8192
    hgate_kernel<<<grid, block, 0, stream>>>(x, y);
}